// Round 1
// baseline (6373.314 us; speedup 1.0000x reference)
//
#include <hip/hip_runtime.h>
#include <stdint.h>

// RNN_Stack: 3-layer leaky-integrator RNN, T=512, B=256, I=64, N=512, TAU=2.
// Weight-stationary layer-pipelined persistent kernel:
//   192 blocks = 3 stages (layers) x 8 rowgroups x 8 coltiles, 1 block/CU.
//   Each block: [32 batch rows x 64 cols] output tile, all T steps.
//   Waves 0,1: q = h_l @ Whh_l (diag zeroed), weights in VGPRs (W^T frags).
//   Waves 2,3: p = n_{l-1} @ Whi + data(t) @ Win (x computed on the fly).
//   h-state carried in f32 registers (MFMA C-layout); ring buffers carry bf16
//   activations between stages; per-(stage,rowgroup,step) LLC arrival counters
//   + __threadfence release/acquire for XCD-safe producer/consumer sync.

#define TS    512
#define BB    256
#define NN    512
#define RD    8      // ring depth (steps)
#define LROW  520    // padded LDS row stride for 512-wide bf16 act tile
#define XROW  72     // padded LDS row stride for 64-wide bf16 x tile
#define PXROW 68     // padded LDS row stride for f32 px tile

typedef __attribute__((ext_vector_type(8))) short s8v;    // 8 bf16 (4 VGPR)
typedef __attribute__((ext_vector_type(4))) float f4v;    // 4 f32
typedef __attribute__((ext_vector_type(4))) unsigned int u4v;

#define MFMA16(a, b, c) __builtin_amdgcn_mfma_f32_16x16x32_bf16((a), (b), (c), 0, 0, 0)

__device__ __forceinline__ short f2bf(float f) {  // RNE f32 -> bf16 bits
  union { float f; unsigned u; } v; v.f = f;
  unsigned u = v.u;
  u += 0x7fffu + ((u >> 16) & 1u);
  return (short)(u >> 16);
}

__device__ __forceinline__ void spin_ge(unsigned* p, unsigned tgt) {
  while (__hip_atomic_load(p, __ATOMIC_RELAXED, __HIP_MEMORY_SCOPE_AGENT) < tgt)
    __builtin_amdgcn_s_sleep(1);
}

__global__ __launch_bounds__(256, 1) void rnn_pipe(
    const float* __restrict__ data, const float* __restrict__ h0,
    const float* __restrict__ Win,  const float* __restrict__ b_in,
    const float* __restrict__ Whh,  const float* __restrict__ b_hh,
    const float* __restrict__ Whi,  const float* __restrict__ b_hi,
    unsigned short* __restrict__ ring, unsigned* __restrict__ cnt,
    float* __restrict__ hfinal)
{
  __shared__ __attribute__((aligned(16))) unsigned short hbuf[32 * LROW];
  __shared__ __attribute__((aligned(16))) unsigned short xbuf[32 * XROW];
  __shared__ __attribute__((aligned(16))) float pxbuf[32 * PXROW];

  const int bi   = blockIdx.x;
  const int rg   = bi & 7;        // rowgroup -> XCD (blockIdx%8 heuristic)
  const int rest = bi >> 3;       // 0..23
  const int lay  = rest >> 3;     // layer/stage 0..2
  const int ct   = rest & 7;      // col tile 0..7
  const int tid  = threadIdx.x;
  const int wv   = tid >> 6;
  const int lane = tid & 63;
  const int lo   = lane & 15;
  const int q4   = lane >> 4;
  const int row0 = rg * 32;
  const bool isQ = (wv < 2);
  const int cb   = ct * 64 + (wv & 1) * 32;  // this wave's 32-col base

  // ---- weight preload into registers: B-frag[k=q4*8+j][n=lo] ----
  s8v WB[16][2];
  s8v WX[2][2];
  {
    const float* Wm = nullptr;
    if (isQ)          Wm = Whh + (size_t)lay * NN * NN;
    else if (lay > 0) Wm = Whi + (size_t)(lay - 1) * NN * NN;
    if (Wm != nullptr) {
      #pragma unroll
      for (int kk = 0; kk < 16; ++kk) {
        #pragma unroll
        for (int nf = 0; nf < 2; ++nf) {
          const int col = cb + nf * 16 + lo;
          s8v v;
          #pragma unroll
          for (int j = 0; j < 8; ++j) {
            const int k = kk * 32 + q4 * 8 + j;
            float f = Wm[(size_t)k * NN + col];
            if (isQ && k == col) f = 0.f;   // forward() zeroes recurrent diag
            v[j] = f2bf(f);
          }
          WB[kk][nf] = v;
        }
      }
    }
    if (!isQ) {
      #pragma unroll
      for (int kk = 0; kk < 2; ++kk) {
        #pragma unroll
        for (int nf = 0; nf < 2; ++nf) {
          const int col = cb + nf * 16 + lo;
          s8v v;
          #pragma unroll
          for (int j = 0; j < 8; ++j) {
            const int k = kk * 32 + q4 * 8 + j;
            v[j] = f2bf(Win[(size_t)k * NN + col]);
          }
          WX[kk][nf] = v;
        }
      }
    }
  }

  // ---- bias and f32 h-state (C-layout: row=q4*4+r, col=lo) ----
  float biasv[2] = {0.f, 0.f};
  f4v hst[2][2];
  if (isQ) {
    #pragma unroll
    for (int nf = 0; nf < 2; ++nf) {
      const int col = cb + nf * 16 + lo;
      float b = b_hh[lay * NN + col] + b_in[col];
      if (lay > 0) b += b_hi[(lay - 1) * NN + col];
      biasv[nf] = b;
    }
    #pragma unroll
    for (int mf = 0; mf < 2; ++mf) {
      #pragma unroll
      for (int nf = 0; nf < 2; ++nf) {
        const int col = cb + nf * 16 + lo;
        #pragma unroll
        for (int r = 0; r < 4; ++r) {
          const int row = row0 + mf * 16 + q4 * 4 + r;
          hst[mf][nf][r] = h0[(size_t)lay * BB * NN + (size_t)row * NN + col];
        }
      }
    }
  }

  const int cself = (lay * 8 + rg) * TS;

  for (int t = 0; t < TS; ++t) {
    const int slot = t & (RD - 1);

    // ---- dependency wait: own-stage lockstep, upstream step t, backpressure
    if (tid == 0) {
      if (t >= 1)             spin_ge(&cnt[cself + t - 1], 8);
      if (lay > 0)            spin_ge(&cnt[((lay - 1) * 8 + rg) * TS + t], 8);
      if (lay < 2 && t >= RD) spin_ge(&cnt[((lay + 1) * 8 + rg) * TS + t - RD], 8);
      __threadfence();  // acquire side (cross-XCD safety)
    }
    __syncthreads();

    // ---- stage hbuf (own h rows, bf16) and xbuf (data tile f32->bf16) ----
    if (t >= 1) {
      const unsigned short* src =
          ring + (size_t)(lay * RD + ((t - 1) & (RD - 1))) * BB * NN + (size_t)row0 * NN;
      #pragma unroll
      for (int c = 0; c < 8; ++c) {
        const int chunk = c * 256 + tid;   // wave reads one full 1KB row
        const int r = chunk >> 6;
        const int s = chunk & 63;
        u4v vv = *(const u4v*)(src + (size_t)r * NN + s * 8);
        *(u4v*)(hbuf + r * LROW + s * 8) = vv;
      }
    }
    {
      const float* dsrc = data + (size_t)t * BB * 64 + (size_t)row0 * 64;
      const int r = tid >> 3, c0 = (tid & 7) * 8;
      f4v a = *(const f4v*)(dsrc + r * 64 + c0);
      f4v b = *(const f4v*)(dsrc + r * 64 + c0 + 4);
      s8v v;
      v[0] = f2bf(a[0]); v[1] = f2bf(a[1]); v[2] = f2bf(a[2]); v[3] = f2bf(a[3]);
      v[4] = f2bf(b[0]); v[5] = f2bf(b[1]); v[6] = f2bf(b[2]); v[7] = f2bf(b[3]);
      *(s8v*)(xbuf + r * XROW + c0) = v;
    }
    __builtin_amdgcn_s_waitcnt(0);
    __syncthreads();

    // ---- MFMA phase ----
    f4v zero4 = {0.f, 0.f, 0.f, 0.f};
    f4v acc[2][2] = {{zero4, zero4}, {zero4, zero4}};

    if (isQ) {
      if (t == 0) {  // A-frags straight from h0 (f32 -> bf16)
        const float* hsrc = h0 + (size_t)lay * BB * NN;
        #pragma unroll
        for (int kk = 0; kk < 16; ++kk) {
          s8v am[2];
          #pragma unroll
          for (int mf = 0; mf < 2; ++mf) {
            const float* rp = hsrc + (size_t)(row0 + mf * 16 + lo) * NN + kk * 32 + q4 * 8;
            f4v fa = *(const f4v*)rp;
            f4v fb = *(const f4v*)(rp + 4);
            s8v v;
            v[0] = f2bf(fa[0]); v[1] = f2bf(fa[1]); v[2] = f2bf(fa[2]); v[3] = f2bf(fa[3]);
            v[4] = f2bf(fb[0]); v[5] = f2bf(fb[1]); v[6] = f2bf(fb[2]); v[7] = f2bf(fb[3]);
            am[mf] = v;
          }
          acc[0][0] = MFMA16(am[0], WB[kk][0], acc[0][0]);
          acc[0][1] = MFMA16(am[0], WB[kk][1], acc[0][1]);
          acc[1][0] = MFMA16(am[1], WB[kk][0], acc[1][0]);
          acc[1][1] = MFMA16(am[1], WB[kk][1], acc[1][1]);
        }
      } else {
        #pragma unroll
        for (int kk = 0; kk < 16; ++kk) {
          s8v a0 = *(const s8v*)(hbuf + (0  + lo) * LROW + kk * 32 + q4 * 8);
          s8v a1 = *(const s8v*)(hbuf + (16 + lo) * LROW + kk * 32 + q4 * 8);
          acc[0][0] = MFMA16(a0, WB[kk][0], acc[0][0]);
          acc[0][1] = MFMA16(a0, WB[kk][1], acc[0][1]);
          acc[1][0] = MFMA16(a1, WB[kk][0], acc[1][0]);
          acc[1][1] = MFMA16(a1, WB[kk][1], acc[1][1]);
        }
      }
    } else {
      if (lay > 0) {  // p = n_{l-1}(t) @ Whi, A-frags direct from ring (L2)
        const unsigned short* psrc = ring + (size_t)((lay - 1) * RD + slot) * BB * NN;
        const unsigned short* p0 = psrc + (size_t)(row0 + 0  + lo) * NN + q4 * 8;
        const unsigned short* p1 = psrc + (size_t)(row0 + 16 + lo) * NN + q4 * 8;
        #pragma unroll
        for (int kk = 0; kk < 16; ++kk) {
          s8v a0 = *(const s8v*)(p0 + kk * 32);
          s8v a1 = *(const s8v*)(p1 + kk * 32);
          acc[0][0] = MFMA16(a0, WB[kk][0], acc[0][0]);
          acc[0][1] = MFMA16(a0, WB[kk][1], acc[0][1]);
          acc[1][0] = MFMA16(a1, WB[kk][0], acc[1][0]);
          acc[1][1] = MFMA16(a1, WB[kk][1], acc[1][1]);
        }
      }
      #pragma unroll
      for (int kk = 0; kk < 2; ++kk) {  // x = data(t) @ Win (K=64)
        s8v a0 = *(const s8v*)(xbuf + (0  + lo) * XROW + kk * 32 + q4 * 8);
        s8v a1 = *(const s8v*)(xbuf + (16 + lo) * XROW + kk * 32 + q4 * 8);
        acc[0][0] = MFMA16(a0, WX[kk][0], acc[0][0]);
        acc[0][1] = MFMA16(a0, WX[kk][1], acc[0][1]);
        acc[1][0] = MFMA16(a1, WX[kk][0], acc[1][0]);
        acc[1][1] = MFMA16(a1, WX[kk][1], acc[1][1]);
      }
      const int cpx = (wv - 2) * 32;
      #pragma unroll
      for (int mf = 0; mf < 2; ++mf)
        #pragma unroll
        for (int nf = 0; nf < 2; ++nf)
          #pragma unroll
          for (int r = 0; r < 4; ++r)
            pxbuf[(mf * 16 + q4 * 4 + r) * PXROW + cpx + nf * 16 + lo] = acc[mf][nf][r];
    }
    __syncthreads();

    // ---- combine (q waves): n = lrelu(0.5*h + 0.5*(q + p + x + bias)) ----
    if (isQ) {
      unsigned short* dst = ring + (size_t)(lay * RD + slot) * BB * NN;
      #pragma unroll
      for (int mf = 0; mf < 2; ++mf) {
        #pragma unroll
        for (int nf = 0; nf < 2; ++nf) {
          #pragma unroll
          for (int r = 0; r < 4; ++r) {
            const int rl = mf * 16 + q4 * 4 + r;
            const int cl = wv * 32 + nf * 16 + lo;
            const float px = pxbuf[rl * PXROW + cl];
            float v = 0.5f * hst[mf][nf][r] + 0.5f * (acc[mf][nf][r] + px + biasv[nf]);
            v = (v >= 0.f) ? v : 0.01f * v;
            hst[mf][nf][r] = v;
            dst[(size_t)(row0 + rl) * NN + (size_t)ct * 64 + cl] = (unsigned short)f2bf(v);
          }
        }
      }
      if (lay == 2 && t == TS - 1) {
        #pragma unroll
        for (int mf = 0; mf < 2; ++mf)
          #pragma unroll
          for (int nf = 0; nf < 2; ++nf)
            #pragma unroll
            for (int r = 0; r < 4; ++r) {
              const int rl = mf * 16 + q4 * 4 + r;
              const int cl = wv * 32 + nf * 16 + lo;
              hfinal[(size_t)(row0 + rl) * NN + ct * 64 + cl] = hst[mf][nf][r];
            }
      }
    }
    __builtin_amdgcn_s_waitcnt(0);
    __syncthreads();
    if (tid == 0) {
      __threadfence();  // release: make ring stores agent-visible
      __hip_atomic_fetch_add(&cnt[cself + t], 1u, __ATOMIC_RELAXED, __HIP_MEMORY_SCOPE_AGENT);
    }
  }
}

// out[256,10] = hfinal @ Wfc + b_fc   (tiny f32 readout)
__global__ void readout_k(const float* __restrict__ hfinal, const float* __restrict__ Wfc,
                          const float* __restrict__ b_fc, float* __restrict__ out)
{
  const int row = blockIdx.x;
  const int lane = threadIdx.x;  // 64
  float a[10];
  #pragma unroll
  for (int c = 0; c < 10; ++c) a[c] = 0.f;
  for (int k = lane; k < NN; k += 64) {
    const float h = hfinal[(size_t)row * NN + k];
    const float* w = Wfc + (size_t)k * 10;
    #pragma unroll
    for (int c = 0; c < 10; ++c) a[c] += h * w[c];
  }
  #pragma unroll
  for (int off = 32; off > 0; off >>= 1) {
    #pragma unroll
    for (int c = 0; c < 10; ++c) a[c] += __shfl_down(a[c], off);
  }
  if (lane == 0) {
    #pragma unroll
    for (int c = 0; c < 10; ++c) out[row * 10 + c] = a[c] + b_fc[c];
  }
}

extern "C" void kernel_launch(void* const* d_in, const int* in_sizes, int n_in,
                              void* d_out, int out_size, void* d_ws, size_t ws_size,
                              hipStream_t stream) {
  (void)in_sizes; (void)n_in; (void)out_size; (void)ws_size;
  const float* data = (const float*)d_in[0];
  const float* h0   = (const float*)d_in[1];
  const float* Win  = (const float*)d_in[2];
  const float* b_in = (const float*)d_in[3];
  const float* Whh  = (const float*)d_in[4];
  const float* b_hh = (const float*)d_in[5];
  const float* Whi  = (const float*)d_in[6];
  const float* b_hi = (const float*)d_in[7];
  const float* Wfc  = (const float*)d_in[8];
  const float* b_fc = (const float*)d_in[9];

  // ws layout: rings (3 x RD x 256 x 512 bf16 = 6 MB) | cnt (48 KB) | hfinal (512 KB)
  unsigned short* ring = (unsigned short*)d_ws;
  const size_t ring_bytes = (size_t)3 * RD * BB * NN * 2;
  unsigned* cnt = (unsigned*)((char*)d_ws + ring_bytes);
  const size_t cnt_bytes = (size_t)3 * 8 * TS * 4;
  float* hfinal = (float*)((char*)d_ws + ring_bytes + 65536);

  hipMemsetAsync(cnt, 0, cnt_bytes, stream);
  hipLaunchKernelGGL(rnn_pipe, dim3(192), dim3(256), 0, stream,
                     data, h0, Win, b_in, Whh, b_hh, Whi, b_hi, ring, cnt, hfinal);
  hipLaunchKernelGGL(readout_k, dim3(256), dim3(64), 0, stream,
                     hfinal, Wfc, b_fc, (float*)d_out);
}